// Round 4
// baseline (592.661 us; speedup 1.0000x reference)
//
#include <hip/hip_runtime.h>
#include <hip/hip_bf16.h>

#define N_TOK 4096
#define DIM   1024
#define NEXP  8
#define FDIM  4096

#define BM 128
#define BN 128
#define BK 64
#define TILE (BM * BK)   // elems per LDS tile buffer

typedef __attribute__((ext_vector_type(8))) short bf16x8;
typedef __attribute__((ext_vector_type(4))) float f32x4;

__device__ __forceinline__ unsigned short f2bf(float f) {
    unsigned u = __builtin_bit_cast(unsigned, f);
    u = (u + 0x7fffu + ((u >> 16) & 1u)) >> 16;
    return (unsigned short)u;
}

// async global->LDS, 16B per lane. LDS dest is wave-uniform base + lane*16.
__device__ __forceinline__ void gld16(const unsigned short* g, unsigned short* l) {
    __builtin_amdgcn_global_load_lds(
        (const __attribute__((address_space(1))) unsigned int*)g,
        (__attribute__((address_space(3))) unsigned int*)l, 16, 0, 0);
}

// ---------------- router: 1 wave per token ----------------
__global__ void router_kernel(const float* __restrict__ x, const float* __restrict__ Wr,
                              int* __restrict__ tk_idx, float* __restrict__ tk_w,
                              int* __restrict__ counts) {
    int n = blockIdx.x;
    int l = threadIdx.x;
    float acc[8];
#pragma unroll
    for (int e = 0; e < 8; e++) acc[e] = 0.f;
    const float* xr = x + (size_t)n * DIM;
#pragma unroll 4
    for (int i = 0; i < 16; i++) {
        int d = i * 64 + l;
        float xv = xr[d];
        const float4* wr = (const float4*)(Wr + (size_t)d * 8);
        float4 w0 = wr[0], w1 = wr[1];
        acc[0] += xv * w0.x; acc[1] += xv * w0.y; acc[2] += xv * w0.z; acc[3] += xv * w0.w;
        acc[4] += xv * w1.x; acc[5] += xv * w1.y; acc[6] += xv * w1.z; acc[7] += xv * w1.w;
    }
#pragma unroll
    for (int off = 32; off >= 1; off >>= 1)
#pragma unroll
        for (int e = 0; e < 8; e++) acc[e] += __shfl_xor(acc[e], off);
    if (l == 0) {
        float mx = acc[0];
#pragma unroll
        for (int e = 1; e < 8; e++) mx = fmaxf(mx, acc[e]);
        float p[8], s = 0.f;
#pragma unroll
        for (int e = 0; e < 8; e++) { p[e] = expf(acc[e] - mx); s += p[e]; }
#pragma unroll
        for (int e = 0; e < 8; e++) p[e] /= s;
        int i0 = 0;
#pragma unroll
        for (int e = 1; e < 8; e++) if (p[e] > p[i0]) i0 = e;
        int i1 = (i0 == 0) ? 1 : 0;
#pragma unroll
        for (int e = 0; e < 8; e++) if (e != i0 && p[e] > p[i1]) i1 = e;
        float w0 = p[i0], w1 = p[i1], s2 = w0 + w1;
        w0 /= s2; w1 /= s2;
        tk_idx[2 * n] = i0; tk_idx[2 * n + 1] = i1;
        tk_w[2 * n] = w0;   tk_w[2 * n + 1] = w1;
        atomicAdd(&counts[i0], 1);
        atomicAdd(&counts[i1], 1);
    }
}

__global__ void scan_kernel(const int* __restrict__ counts, int* __restrict__ offs,
                            int* __restrict__ cursor) {
    if (threadIdx.x == 0 && blockIdx.x == 0) {
        int a = 0;
        for (int e = 0; e < NEXP; e++) { offs[e] = a; cursor[e] = a; a += counts[e]; }
        offs[NEXP] = a;
    }
}

__global__ void fill_kernel(const int* __restrict__ tk_idx, int* __restrict__ cursor,
                            int* __restrict__ perm) {
    int n = blockIdx.x * blockDim.x + threadIdx.x;
    if (n >= N_TOK) return;
    int i0 = tk_idx[2 * n], i1 = tk_idx[2 * n + 1];
    int p0 = atomicAdd(&cursor[i0], 1);
    perm[p0] = 2 * n;
    int p1 = atomicAdd(&cursor[i1], 1);
    perm[p1] = 2 * n + 1;
}

// gather x rows (fp32) -> xb (bf16), permuted row space; 2 rows per block
__global__ void gather_kernel(const float* __restrict__ x, const int* __restrict__ perm,
                              unsigned short* __restrict__ xb) {
    int p = blockIdx.x * 2 + (threadIdx.x >> 7);
    int c = (threadIdx.x & 127) * 8;
    int tok = perm[p] >> 1;
    const float4* src = (const float4*)(x + (size_t)tok * DIM + c);
    float4 a = src[0], b = src[1];
    unsigned short o[8] = {f2bf(a.x), f2bf(a.y), f2bf(a.z), f2bf(a.w),
                           f2bf(b.x), f2bf(b.y), f2bf(b.z), f2bf(b.w)};
    *(int4*)(xb + (size_t)p * DIM + c) = *(const int4*)o;
}

// transpose + fp32->bf16: in [E][R][C] -> out [E][C][R], 64x64 tiles, vectorized
__global__ __launch_bounds__(256) void transpose_conv_kernel(
    const float* __restrict__ in, unsigned short* __restrict__ out, int R, int C) {
    __shared__ float tl[64][65];
    int e = blockIdx.z;
    const float* ip = in + (size_t)e * R * C;
    unsigned short* op = out + (size_t)e * R * C;
    int c0 = blockIdx.x * 64, r0 = blockIdx.y * 64;
    int t = threadIdx.x;
    int lr = t >> 4, lc = (t & 15) * 4;
#pragma unroll
    for (int it = 0; it < 4; it++) {
        int r = lr + it * 16;
        float4 v = *(const float4*)(ip + (size_t)(r0 + r) * C + c0 + lc);
        tl[lc + 0][r] = v.x; tl[lc + 1][r] = v.y; tl[lc + 2][r] = v.z; tl[lc + 3][r] = v.w;
    }
    __syncthreads();
    int orow = t >> 3, orr = (t & 7) * 8;
#pragma unroll
    for (int it = 0; it < 2; it++) {
        int oc = orow + it * 32;
        float4 a = *(const float4*)&tl[oc][orr];
        float4 b = *(const float4*)&tl[oc][orr + 4];
        unsigned short o[8] = {f2bf(a.x), f2bf(a.y), f2bf(a.z), f2bf(a.w),
                               f2bf(b.x), f2bf(b.y), f2bf(b.z), f2bf(b.w)};
        *(int4*)(op + (size_t)(c0 + oc) * R + r0 + orr) = *(const int4*)o;
    }
}

// ---------------- GEMM core: counted-vmcnt 2-phase + T2 swizzle, BK=64 ----------------
// LDS logical tile [128 rows][64 k] bf16; 16B block b of row r stored at phys block b^(r&7).
// global_load_lds dest is linear; source per-lane address carries the inverse swizzle.

#define GEMM_CORE(K_, A_, B_)                                                           \
    __shared__ unsigned short As[2 * TILE];                                             \
    __shared__ unsigned short Bs[2 * TILE];                                             \
    int t = threadIdx.x;                                                                \
    int lane = t & 63, wid = t >> 6;                                                    \
    int wm = wid >> 1, wn = wid & 1;                                                    \
    int arow_base = rt * BM;                                                            \
    int l8 = lane >> 3;            /* 0..7 : row within 8-row stripe */                 \
    int lb = lane & 7;             /* 0..7 : 16B block (phys) */                        \
    int swzb = (lb ^ l8) * 8;      /* inverse-swizzled logical k-elem offset */         \
    const unsigned short* gA[4];                                                        \
    const unsigned short* gB[4];                                                        \
    _Pragma("unroll")                                                                   \
    for (int j = 0; j < 4; j++) {                                                       \
        int ra = min(arow_base + wid * 32 + j * 8 + l8, cnt - 1);                       \
        gA[j] = A_ + (size_t)ra * K_ + swzb;                                            \
        gB[j] = B_ + (size_t)(n0 + wid * 32 + j * 8 + l8) * K_ + swzb;                  \
    }                                                                                   \
    unsigned short* lA = As + wid * 32 * BK;                                            \
    unsigned short* lB = Bs + wid * 32 * BK;                                            \
    f32x4 acc[4][4];                                                                    \
    _Pragma("unroll")                                                                   \
    for (int i = 0; i < 4; i++)                                                         \
        _Pragma("unroll")                                                               \
        for (int j = 0; j < 4; j++) acc[i][j] = (f32x4){0.f, 0.f, 0.f, 0.f};            \
    int rl = lane & 15;                                                                 \
    int kq = lane >> 4;            /* 0..3 */                                           \
    int rx = rl & 7;                                                                    \
    auto stage = [&](int buf) {                                                         \
        int bo = buf * TILE;                                                            \
        _Pragma("unroll")                                                               \
        for (int j = 0; j < 4; j++) { gld16(gA[j], lA + bo + j * 8 * BK); gA[j] += BK; }\
        _Pragma("unroll")                                                               \
        for (int j = 0; j < 4; j++) { gld16(gB[j], lB + bo + j * 8 * BK); gB[j] += BK; }\
    };                                                                                  \
    auto compute = [&](int buf) {                                                       \
        const unsigned short* as = As + buf * TILE;                                     \
        const unsigned short* bs = Bs + buf * TILE;                                     \
        bf16x8 af[4][2], bfr[4][2];                                                     \
        _Pragma("unroll")                                                               \
        for (int mf = 0; mf < 4; mf++)                                                  \
            _Pragma("unroll")                                                           \
            for (int ks = 0; ks < 2; ks++)                                              \
                af[mf][ks] = *(const bf16x8*)(as + (wm * 64 + mf * 16 + rl) * BK        \
                                              + (((ks * 4 + kq) ^ rx) * 8));            \
        _Pragma("unroll")                                                               \
        for (int nf = 0; nf < 4; nf++)                                                  \
            _Pragma("unroll")                                                           \
            for (int ks = 0; ks < 2; ks++)                                              \
                bfr[nf][ks] = *(const bf16x8*)(bs + (wn * 64 + nf * 16 + rl) * BK       \
                                               + (((ks * 4 + kq) ^ rx) * 8));           \
        _Pragma("unroll")                                                               \
        for (int ks = 0; ks < 2; ks++)                                                  \
            _Pragma("unroll")                                                           \
            for (int mf = 0; mf < 4; mf++)                                              \
                _Pragma("unroll")                                                       \
                for (int nf = 0; nf < 4; nf++)                                          \
                    acc[mf][nf] = __builtin_amdgcn_mfma_f32_16x16x32_bf16(              \
                        af[mf][ks], bfr[nf][ks], acc[mf][nf], 0, 0, 0);                 \
    };                                                                                  \
    const int NT = K_ / BK;                                                             \
    stage(0);                                                                           \
    int cur = 0;                                                                        \
    for (int it = 0; it < NT - 1; ++it) {                                               \
        stage(cur ^ 1);                                                                 \
        asm volatile("s_waitcnt vmcnt(8)" ::: "memory");  /* cur's 8 loads done */      \
        __builtin_amdgcn_s_barrier();                                                   \
        compute(cur);                                                                   \
        __builtin_amdgcn_s_barrier();                                                   \
        cur ^= 1;                                                                       \
    }                                                                                   \
    asm volatile("s_waitcnt vmcnt(0)" ::: "memory");                                    \
    __builtin_amdgcn_s_barrier();                                                       \
    compute(cur);

// GEMM1: h = gelu(xb @ w1t^T)  (K=1024, N=4096); 1-D grid, XCD chunked swizzle
__global__ __launch_bounds__(256) void gemm1_kernel(
    const unsigned short* __restrict__ xb, const unsigned short* __restrict__ w1t,
    unsigned short* __restrict__ h, const int* __restrict__ counts, const int* __restrict__ offs) {
    const int NTX = N_TOK / BM;
    const int NTY = FDIM / BN;
    const int nwg = NTX * NTY * NEXP;
    int L = blockIdx.x;
    int pos = (L & 7) * (nwg >> 3) + (L >> 3);
    int rt = pos % NTX;
    int tmp = pos / NTX;
    int n0 = (tmp % NTY) * BN;
    int e = tmp / NTY;
    int cnt = counts[e];
    if (rt * BM >= cnt) return;
    int off = offs[e];
    const unsigned short* Ap = xb + (size_t)off * DIM;
    const unsigned short* Bp = w1t + (size_t)e * FDIM * DIM;

    GEMM_CORE(DIM, Ap, Bp)

    int rq = lane >> 4;
#pragma unroll
    for (int mf = 0; mf < 4; mf++) {
#pragma unroll
        for (int r = 0; r < 4; r++) {
            int row_local = wm * 64 + mf * 16 + rq * 4 + r;
            int grow = arow_base + row_local;
            if (grow < cnt) {
                unsigned short* hp = h + (size_t)(off + grow) * FDIM + n0 + wn * 64;
#pragma unroll
                for (int nf = 0; nf < 4; nf++) {
                    float v = acc[mf][nf][r];
                    float g = 0.5f * v * (1.0f + erff(v * 0.70710678118654752f));
                    hp[nf * 16 + rl] = f2bf(g);
                }
            }
        }
    }
}

// GEMM2: y = h @ w2t^T, weighted scatter-add (K=4096, N=1024)
__global__ __launch_bounds__(256) void gemm2_kernel(
    const unsigned short* __restrict__ h, const unsigned short* __restrict__ w2t,
    float* __restrict__ out, const int* __restrict__ counts, const int* __restrict__ offs,
    const int* __restrict__ perm, const float* __restrict__ tk_w) {
    const int NTX = N_TOK / BM;
    const int NTY = DIM / BN;
    const int nwg = NTX * NTY * NEXP;
    int L = blockIdx.x;
    int pos = (L & 7) * (nwg >> 3) + (L >> 3);
    int rt = pos % NTX;
    int tmp = pos / NTX;
    int n0 = (tmp % NTY) * BN;
    int e = tmp / NTY;
    int cnt = counts[e];
    if (rt * BM >= cnt) return;
    int off = offs[e];
    const unsigned short* Ap = h + (size_t)off * FDIM;
    const unsigned short* Bp = w2t + (size_t)e * DIM * FDIM;

    GEMM_CORE(FDIM, Ap, Bp)

    int rq = lane >> 4;
#pragma unroll
    for (int mf = 0; mf < 4; mf++) {
#pragma unroll
        for (int r = 0; r < 4; r++) {
            int row_local = wm * 64 + mf * 16 + rq * 4 + r;
            int grow = arow_base + row_local;
            if (grow < cnt) {
                int pv = perm[off + grow];
                float wgt = tk_w[pv];
                float* op = out + (size_t)(pv >> 1) * DIM + n0 + wn * 64;
#pragma unroll
                for (int nf = 0; nf < 4; nf++)
                    atomicAdd(&op[nf * 16 + rl], wgt * acc[mf][nf][r]);
            }
        }
    }
}

extern "C" void kernel_launch(void* const* d_in, const int* in_sizes, int n_in,
                              void* d_out, int out_size, void* d_ws, size_t ws_size,
                              hipStream_t stream) {
    const float* x  = (const float*)d_in[0];
    const float* Wr = (const float*)d_in[1];
    const float* W1 = (const float*)d_in[2];
    const float* W2 = (const float*)d_in[3];
    float* out = (float*)d_out;

    char* w = (char*)d_ws;
    int*   counts = (int*)(w + 0);
    int*   offs   = (int*)(w + 64);
    int*   cursor = (int*)(w + 128);
    int*   tk_idx = (int*)(w + 256);
    float* tk_w   = (float*)(w + 256 + 32768);
    int*   perm   = (int*)(w + 256 + 65536);
    size_t base = (size_t)1 << 20;
    unsigned short* xb   = (unsigned short*)(w + base);
    unsigned short* hbuf = (unsigned short*)(w + base + ((size_t)16 << 20));
    unsigned short* w1t  = (unsigned short*)(w + base + ((size_t)80 << 20));
    unsigned short* w2t  = (unsigned short*)(w + base + ((size_t)144 << 20));

    hipMemsetAsync(d_out, 0, (size_t)out_size * sizeof(float), stream);
    hipMemsetAsync(w, 0, 256, stream);

    router_kernel<<<N_TOK, 64, 0, stream>>>(x, Wr, tk_idx, tk_w, counts);
    scan_kernel<<<1, 64, 0, stream>>>(counts, offs, cursor);
    fill_kernel<<<N_TOK / 256, 256, 0, stream>>>(tk_idx, cursor, perm);
    gather_kernel<<<N_TOK, 256, 0, stream>>>(x, perm, xb);

    // W1 [E][1024][4096] -> w1t [E][4096][1024]
    transpose_conv_kernel<<<dim3(FDIM / 64, DIM / 64, NEXP), 256, 0, stream>>>(W1, w1t, DIM, FDIM);
    // W2 [E][4096][1024] -> w2t [E][1024][4096]
    transpose_conv_kernel<<<dim3(DIM / 64, FDIM / 64, NEXP), 256, 0, stream>>>(W2, w2t, FDIM, DIM);

    gemm1_kernel<<<(N_TOK / BM) * (FDIM / BN) * NEXP, 256, 0, stream>>>(xb, w1t, hbuf, counts, offs);
    gemm2_kernel<<<(N_TOK / BM) * (DIM / BN) * NEXP, 256, 0, stream>>>(hbuf, w2t, out, counts, offs, perm, tk_w);
}

// Round 5
// 501.447 us; speedup vs baseline: 1.1819x; 1.1819x over previous
//
#include <hip/hip_runtime.h>
#include <hip/hip_bf16.h>

#define N_TOK 4096
#define DIM   1024
#define NEXP  8
#define FDIM  4096

#define BM 128
#define BN 128
#define BK 32
#define TILE (BM * BK)   // elems per LDS tile buffer (8 KB)

typedef __attribute__((ext_vector_type(8))) short bf16x8;
typedef __attribute__((ext_vector_type(4))) float f32x4;

__device__ __forceinline__ unsigned short f2bf(float f) {
    unsigned u = __builtin_bit_cast(unsigned, f);
    u = (u + 0x7fffu + ((u >> 16) & 1u)) >> 16;
    return (unsigned short)u;
}

// async global->LDS, 16B per lane. LDS dest is wave-uniform base + lane*16.
__device__ __forceinline__ void gld16(const unsigned short* g, unsigned short* l) {
    __builtin_amdgcn_global_load_lds(
        (const __attribute__((address_space(1))) unsigned int*)g,
        (__attribute__((address_space(3))) unsigned int*)l, 16, 0, 0);
}

// ---------------- router: 1 wave per token ----------------
__global__ void router_kernel(const float* __restrict__ x, const float* __restrict__ Wr,
                              int* __restrict__ tk_idx, float* __restrict__ tk_w,
                              int* __restrict__ counts) {
    int n = blockIdx.x;
    int l = threadIdx.x;
    float acc[8];
#pragma unroll
    for (int e = 0; e < 8; e++) acc[e] = 0.f;
    const float* xr = x + (size_t)n * DIM;
#pragma unroll 4
    for (int i = 0; i < 16; i++) {
        int d = i * 64 + l;
        float xv = xr[d];
        const float4* wr = (const float4*)(Wr + (size_t)d * 8);
        float4 w0 = wr[0], w1 = wr[1];
        acc[0] += xv * w0.x; acc[1] += xv * w0.y; acc[2] += xv * w0.z; acc[3] += xv * w0.w;
        acc[4] += xv * w1.x; acc[5] += xv * w1.y; acc[6] += xv * w1.z; acc[7] += xv * w1.w;
    }
#pragma unroll
    for (int off = 32; off >= 1; off >>= 1)
#pragma unroll
        for (int e = 0; e < 8; e++) acc[e] += __shfl_xor(acc[e], off);
    if (l == 0) {
        float mx = acc[0];
#pragma unroll
        for (int e = 1; e < 8; e++) mx = fmaxf(mx, acc[e]);
        float p[8], s = 0.f;
#pragma unroll
        for (int e = 0; e < 8; e++) { p[e] = expf(acc[e] - mx); s += p[e]; }
#pragma unroll
        for (int e = 0; e < 8; e++) p[e] /= s;
        int i0 = 0;
#pragma unroll
        for (int e = 1; e < 8; e++) if (p[e] > p[i0]) i0 = e;
        int i1 = (i0 == 0) ? 1 : 0;
#pragma unroll
        for (int e = 0; e < 8; e++) if (e != i0 && p[e] > p[i1]) i1 = e;
        float w0 = p[i0], w1 = p[i1], s2 = w0 + w1;
        w0 /= s2; w1 /= s2;
        tk_idx[2 * n] = i0; tk_idx[2 * n + 1] = i1;
        tk_w[2 * n] = w0;   tk_w[2 * n + 1] = w1;
        atomicAdd(&counts[i0], 1);
        atomicAdd(&counts[i1], 1);
    }
}

__global__ void scan_kernel(const int* __restrict__ counts, int* __restrict__ offs,
                            int* __restrict__ cursor) {
    if (threadIdx.x == 0 && blockIdx.x == 0) {
        int a = 0;
        for (int e = 0; e < NEXP; e++) { offs[e] = a; cursor[e] = a; a += counts[e]; }
        offs[NEXP] = a;
    }
}

__global__ void fill_kernel(const int* __restrict__ tk_idx, int* __restrict__ cursor,
                            int* __restrict__ perm) {
    int n = blockIdx.x * blockDim.x + threadIdx.x;
    if (n >= N_TOK) return;
    int i0 = tk_idx[2 * n], i1 = tk_idx[2 * n + 1];
    int p0 = atomicAdd(&cursor[i0], 1);
    perm[p0] = 2 * n;
    int p1 = atomicAdd(&cursor[i1], 1);
    perm[p1] = 2 * n + 1;
}

// gather x rows (fp32) -> xb (bf16), permuted row space; 2 rows per block
__global__ void gather_kernel(const float* __restrict__ x, const int* __restrict__ perm,
                              unsigned short* __restrict__ xb) {
    int p = blockIdx.x * 2 + (threadIdx.x >> 7);
    int c = (threadIdx.x & 127) * 8;
    int tok = perm[p] >> 1;
    const float4* src = (const float4*)(x + (size_t)tok * DIM + c);
    float4 a = src[0], b = src[1];
    unsigned short o[8] = {f2bf(a.x), f2bf(a.y), f2bf(a.z), f2bf(a.w),
                           f2bf(b.x), f2bf(b.y), f2bf(b.z), f2bf(b.w)};
    *(int4*)(xb + (size_t)p * DIM + c) = *(const int4*)o;
}

// transpose + fp32->bf16: in [E][R][C] -> out [E][C][R], 64x64 tiles, vectorized
__global__ __launch_bounds__(256) void transpose_conv_kernel(
    const float* __restrict__ in, unsigned short* __restrict__ out, int R, int C) {
    __shared__ float tl[64][65];
    int e = blockIdx.z;
    const float* ip = in + (size_t)e * R * C;
    unsigned short* op = out + (size_t)e * R * C;
    int c0 = blockIdx.x * 64, r0 = blockIdx.y * 64;
    int t = threadIdx.x;
    int lr = t >> 4, lc = (t & 15) * 4;
#pragma unroll
    for (int it = 0; it < 4; it++) {
        int r = lr + it * 16;
        float4 v = *(const float4*)(ip + (size_t)(r0 + r) * C + c0 + lc);
        tl[lc + 0][r] = v.x; tl[lc + 1][r] = v.y; tl[lc + 2][r] = v.z; tl[lc + 3][r] = v.w;
    }
    __syncthreads();
    int orow = t >> 3, orr = (t & 7) * 8;
#pragma unroll
    for (int it = 0; it < 2; it++) {
        int oc = orow + it * 32;
        float4 a = *(const float4*)&tl[oc][orr];
        float4 b = *(const float4*)&tl[oc][orr + 4];
        unsigned short o[8] = {f2bf(a.x), f2bf(a.y), f2bf(a.z), f2bf(a.w),
                               f2bf(b.x), f2bf(b.y), f2bf(b.z), f2bf(b.w)};
        *(int4*)(op + (size_t)(c0 + oc) * R + r0 + orr) = *(const int4*)o;
    }
}

// ---------------- GEMM core: 3-buffer ring, 2-deep counted vmcnt, free-2-way swizzle ----------------
// LDS logical tile [128 rows][32 k] bf16 (64B rows = 4x16B blocks).
// Swizzle: phys 16B-block = logical_block ^ ((row>>1)&3)  -> frag reads tile the 128B
// bank space exactly 2x (free). Inverse swizzle applied on the per-lane GLOBAL source;
// global_load_lds dest stays linear (rule: both-sides-or-neither).

#define GEMM_CORE(K_, A_, B_)                                                           \
    __shared__ unsigned short As[3 * TILE];                                             \
    __shared__ unsigned short Bs[3 * TILE];                                             \
    int t = threadIdx.x;                                                                \
    int lane = t & 63, wid = t >> 6;                                                    \
    int wm = wid >> 1, wn = wid & 1;                                                    \
    int arow_base = rt * BM;                                                            \
    /* staging decode: wave-load = 16 rows x 64B, dest linear lane*16B */               \
    int srow = lane >> 2;                       /* row within 16-row segment */         \
    int logb = (lane & 3) ^ ((lane >> 3) & 3);  /* inverse-swizzled 16B block */        \
    const unsigned short* gA[2];                                                        \
    const unsigned short* gB[2];                                                        \
    _Pragma("unroll")                                                                   \
    for (int j = 0; j < 2; j++) {                                                       \
        int ra = min(arow_base + wid * 32 + j * 16 + srow, cnt - 1);                    \
        gA[j] = A_ + (size_t)ra * K_ + logb * 8;                                        \
        gB[j] = B_ + (size_t)(n0 + wid * 32 + j * 16 + srow) * K_ + logb * 8;           \
    }                                                                                   \
    f32x4 acc[4][4];                                                                    \
    _Pragma("unroll")                                                                   \
    for (int i = 0; i < 4; i++)                                                         \
        _Pragma("unroll")                                                               \
        for (int j = 0; j < 4; j++) acc[i][j] = (f32x4){0.f, 0.f, 0.f, 0.f};            \
    int rl = lane & 15;                                                                 \
    int kq = lane >> 4;                                                                 \
    int pb8 = (kq ^ ((rl >> 1) & 3)) * 8;       /* phys block offset for frag reads */  \
    auto stage = [&](int buf) {                                                         \
        unsigned short* la = As + buf * TILE + wid * 32 * BK;                           \
        unsigned short* lb = Bs + buf * TILE + wid * 32 * BK;                           \
        _Pragma("unroll")                                                               \
        for (int j = 0; j < 2; j++) { gld16(gA[j], la + j * 16 * BK); gA[j] += BK; }    \
        _Pragma("unroll")                                                               \
        for (int j = 0; j < 2; j++) { gld16(gB[j], lb + j * 16 * BK); gB[j] += BK; }    \
    };                                                                                  \
    auto compute = [&](int buf) {                                                       \
        const unsigned short* as = As + buf * TILE;                                     \
        const unsigned short* bs = Bs + buf * TILE;                                     \
        bf16x8 af[4], bfr[4];                                                           \
        _Pragma("unroll")                                                               \
        for (int mf = 0; mf < 4; mf++)                                                  \
            af[mf] = *(const bf16x8*)(as + (wm * 64 + mf * 16 + rl) * BK + pb8);        \
        _Pragma("unroll")                                                               \
        for (int nf = 0; nf < 4; nf++)                                                  \
            bfr[nf] = *(const bf16x8*)(bs + (wn * 64 + nf * 16 + rl) * BK + pb8);       \
        _Pragma("unroll")                                                               \
        for (int mf = 0; mf < 4; mf++)                                                  \
            _Pragma("unroll")                                                           \
            for (int nf = 0; nf < 4; nf++)                                              \
                acc[mf][nf] = __builtin_amdgcn_mfma_f32_16x16x32_bf16(                  \
                    af[mf], bfr[nf], acc[mf][nf], 0, 0, 0);                             \
    };                                                                                  \
    const int NT = K_ / BK;                                                             \
    stage(0); stage(1);                                                                 \
    int cb = 0;                                                                         \
    for (int it = 0; it < NT - 2; ++it) {                                               \
        int sb = cb + 2; if (sb >= 3) sb -= 3;                                          \
        stage(sb);                                                                      \
        asm volatile("s_waitcnt vmcnt(8)" ::: "memory"); /* drain tile t, keep t+1,t+2 */ \
        __builtin_amdgcn_s_barrier();                                                   \
        compute(cb);                                                                    \
        __builtin_amdgcn_s_barrier();                                                   \
        cb = cb + 1; if (cb >= 3) cb -= 3;                                              \
    }                                                                                   \
    asm volatile("s_waitcnt vmcnt(4)" ::: "memory");                                    \
    __builtin_amdgcn_s_barrier();                                                       \
    compute(cb);                                                                        \
    __builtin_amdgcn_s_barrier();                                                       \
    cb = cb + 1; if (cb >= 3) cb -= 3;                                                  \
    asm volatile("s_waitcnt vmcnt(0)" ::: "memory");                                    \
    __builtin_amdgcn_s_barrier();                                                       \
    compute(cb);

// GEMM1: h = gelu(xb @ w1t^T)  (K=1024, N=4096); 1-D grid, XCD chunked swizzle
__global__ __launch_bounds__(256) void gemm1_kernel(
    const unsigned short* __restrict__ xb, const unsigned short* __restrict__ w1t,
    unsigned short* __restrict__ h, const int* __restrict__ counts, const int* __restrict__ offs) {
    const int NTX = N_TOK / BM;
    const int NTY = FDIM / BN;
    const int nwg = NTX * NTY * NEXP;
    int L = blockIdx.x;
    int pos = (L & 7) * (nwg >> 3) + (L >> 3);
    int rt = pos % NTX;
    int tmp = pos / NTX;
    int n0 = (tmp % NTY) * BN;
    int e = tmp / NTY;
    int cnt = counts[e];
    if (rt * BM >= cnt) return;
    int off = offs[e];
    const unsigned short* Ap = xb + (size_t)off * DIM;
    const unsigned short* Bp = w1t + (size_t)e * FDIM * DIM;

    GEMM_CORE(DIM, Ap, Bp)

    int rq = lane >> 4;
#pragma unroll
    for (int mf = 0; mf < 4; mf++) {
#pragma unroll
        for (int r = 0; r < 4; r++) {
            int row_local = wm * 64 + mf * 16 + rq * 4 + r;
            int grow = arow_base + row_local;
            if (grow < cnt) {
                unsigned short* hp = h + (size_t)(off + grow) * FDIM + n0 + wn * 64;
#pragma unroll
                for (int nf = 0; nf < 4; nf++) {
                    float v = acc[mf][nf][r];
                    float g = 0.5f * v * (1.0f + erff(v * 0.70710678118654752f));
                    hp[nf * 16 + rl] = f2bf(g);
                }
            }
        }
    }
}

// GEMM2: y = h @ w2t^T, weighted scatter-add (K=4096, N=1024)
__global__ __launch_bounds__(256) void gemm2_kernel(
    const unsigned short* __restrict__ h, const unsigned short* __restrict__ w2t,
    float* __restrict__ out, const int* __restrict__ counts, const int* __restrict__ offs,
    const int* __restrict__ perm, const float* __restrict__ tk_w) {
    const int NTX = N_TOK / BM;
    const int NTY = DIM / BN;
    const int nwg = NTX * NTY * NEXP;
    int L = blockIdx.x;
    int pos = (L & 7) * (nwg >> 3) + (L >> 3);
    int rt = pos % NTX;
    int tmp = pos / NTX;
    int n0 = (tmp % NTY) * BN;
    int e = tmp / NTY;
    int cnt = counts[e];
    if (rt * BM >= cnt) return;
    int off = offs[e];
    const unsigned short* Ap = h + (size_t)off * FDIM;
    const unsigned short* Bp = w2t + (size_t)e * DIM * FDIM;

    GEMM_CORE(FDIM, Ap, Bp)

    int rq = lane >> 4;
#pragma unroll
    for (int mf = 0; mf < 4; mf++) {
#pragma unroll
        for (int r = 0; r < 4; r++) {
            int row_local = wm * 64 + mf * 16 + rq * 4 + r;
            int grow = arow_base + row_local;
            if (grow < cnt) {
                int pv = perm[off + grow];
                float wgt = tk_w[pv];
                float* op = out + (size_t)(pv >> 1) * DIM + n0 + wn * 64;
#pragma unroll
                for (int nf = 0; nf < 4; nf++)
                    atomicAdd(&op[nf * 16 + rl], wgt * acc[mf][nf][r]);
            }
        }
    }
}

extern "C" void kernel_launch(void* const* d_in, const int* in_sizes, int n_in,
                              void* d_out, int out_size, void* d_ws, size_t ws_size,
                              hipStream_t stream) {
    const float* x  = (const float*)d_in[0];
    const float* Wr = (const float*)d_in[1];
    const float* W1 = (const float*)d_in[2];
    const float* W2 = (const float*)d_in[3];
    float* out = (float*)d_out;

    char* w = (char*)d_ws;
    int*   counts = (int*)(w + 0);
    int*   offs   = (int*)(w + 64);
    int*   cursor = (int*)(w + 128);
    int*   tk_idx = (int*)(w + 256);
    float* tk_w   = (float*)(w + 256 + 32768);
    int*   perm   = (int*)(w + 256 + 65536);
    size_t base = (size_t)1 << 20;
    unsigned short* xb   = (unsigned short*)(w + base);
    unsigned short* hbuf = (unsigned short*)(w + base + ((size_t)16 << 20));
    unsigned short* w1t  = (unsigned short*)(w + base + ((size_t)80 << 20));
    unsigned short* w2t  = (unsigned short*)(w + base + ((size_t)144 << 20));

    hipMemsetAsync(d_out, 0, (size_t)out_size * sizeof(float), stream);
    hipMemsetAsync(w, 0, 256, stream);

    router_kernel<<<N_TOK, 64, 0, stream>>>(x, Wr, tk_idx, tk_w, counts);
    scan_kernel<<<1, 64, 0, stream>>>(counts, offs, cursor);
    fill_kernel<<<N_TOK / 256, 256, 0, stream>>>(tk_idx, cursor, perm);
    gather_kernel<<<N_TOK, 256, 0, stream>>>(x, perm, xb);

    // W1 [E][1024][4096] -> w1t [E][4096][1024]
    transpose_conv_kernel<<<dim3(FDIM / 64, DIM / 64, NEXP), 256, 0, stream>>>(W1, w1t, DIM, FDIM);
    // W2 [E][4096][1024] -> w2t [E][1024][4096]
    transpose_conv_kernel<<<dim3(DIM / 64, FDIM / 64, NEXP), 256, 0, stream>>>(W2, w2t, FDIM, DIM);

    gemm1_kernel<<<(N_TOK / BM) * (FDIM / BN) * NEXP, 256, 0, stream>>>(xb, w1t, hbuf, counts, offs);
    gemm2_kernel<<<(N_TOK / BM) * (DIM / BN) * NEXP, 256, 0, stream>>>(hbuf, w2t, out, counts, offs, perm, tk_w);
}